// Round 8
// baseline (200.056 us; speedup 1.0000x reference)
//
#include <hip/hip_runtime.h>
#include <hip/hip_fp16.h>

#define NN 50000
#define NE 800000
#define E2 850000   // NE + NN self-loops
#define SCAN_NB 49  // ceil(NN / 1024)
#define GEMM_BLKS 782  // ceil(NN / 64)
#define RANK_BLKS 3321 // ceil(E2 / 256)

static inline int cdiv(long long a, int b) { return (int)((a + b - 1) / b); }

using half8  = __attribute__((ext_vector_type(8))) _Float16;
using floatx4 = __attribute__((ext_vector_type(4))) float;

struct __align__(16) h2x4 { __half2 a, b, c, d; };
struct __align__(8)  h2x2 { __half2 a, b; };

__device__ __forceinline__ void edge_sd(const int* __restrict__ ei, int e, int& s, int& d) {
    if (e < NE) { s = ei[e]; d = ei[NE + e]; }
    else { s = e - NE; d = s; }
}

// ---------------- fused: rank-claim (latency) + fp16 conversions (BW) ----------------
__global__ __launch_bounds__(256) void prep_rank(const int* __restrict__ ei,
                                                 int* __restrict__ deg,
                                                 int* __restrict__ rank,
                                                 const float* __restrict__ x, __half* __restrict__ x16,
                                                 const float* __restrict__ w1, __half* __restrict__ wt1,
                                                 const float* __restrict__ w2, __half* __restrict__ wt2,
                                                 const float* __restrict__ w3, __half* __restrict__ wt3) {
    int b = blockIdx.x;
    if (b < RANK_BLKS) {
        int e = b * 256 + threadIdx.x;
        if (e < E2) {
            int d = (e < NE) ? ei[NE + e] : (e - NE);
            rank[e] = atomicAdd(&deg[d], 1);
        }
        return;
    }
    int tid = (b - RANK_BLKS) * 256 + threadIdx.x;
    int stride = (gridDim.x - RANK_BLKS) * 256;
    for (int i = tid; i < NN * 32; i += stride) {
        float4 v = *(const float4*)&x[(size_t)i * 4];
        h2x2 st;
        st.a = __floats2half2_rn(v.x, v.y);
        st.b = __floats2half2_rn(v.z, v.w);
        *(h2x2*)&x16[(size_t)i * 4] = st;
    }
    for (int i = tid; i < 128 * 128; i += stride)
        wt1[i] = __float2half(w1[(i & 127) * 128 + (i >> 7)]);
    for (int i = tid; i < 128 * 128; i += stride)
        wt2[i] = __float2half(w2[(i & 127) * 128 + (i >> 7)]);
    for (int i = tid; i < 40 * 128; i += stride)
        wt3[i] = __float2half(w3[(i & 127) * 40 + (i >> 7)]);
}

// ---------------- single-kernel two-level scan (49 co-resident blocks + spin) ----------------
__global__ __launch_bounds__(256) void scan_all(const int* __restrict__ deg,
                                                int* __restrict__ rowp,
                                                int* __restrict__ bsums,
                                                int* __restrict__ ctr) {
    __shared__ int wsum[4];
    __shared__ int sh_pref[64];
    int tid = threadIdx.x;
    int base = blockIdx.x * 1024 + tid * 4;
    int4 v = make_int4(0, 0, 0, 0);
    if (base + 3 < NN) v = *(const int4*)&deg[base];
    else {
        if (base + 0 < NN) v.x = deg[base + 0];
        if (base + 1 < NN) v.y = deg[base + 1];
        if (base + 2 < NN) v.z = deg[base + 2];
    }
    v.y += v.x; v.z += v.y; v.w += v.z;
    int lane = tid & 63;
    int wid = tid >> 6;
    int t = v.w;
#pragma unroll
    for (int off = 1; off < 64; off <<= 1) {
        int u = __shfl_up(t, off, 64);
        if (lane >= off) t += u;
    }
    int excl = t - v.w;
    if (lane == 63) wsum[wid] = t;
    __syncthreads();
    int woff = 0;
    for (int w = 0; w < wid; ++w) woff += wsum[w];
    int add = excl + woff;
    if (tid == 255) {
        bsums[blockIdx.x] = add + v.w;
        __threadfence();
        atomicAdd(ctr, 1);
    }
    if (tid == 0) {
        while (__hip_atomic_load(ctr, __ATOMIC_ACQUIRE, __HIP_MEMORY_SCOPE_AGENT) < SCAN_NB) {
            __builtin_amdgcn_s_sleep(8);
        }
    }
    __syncthreads();
    if (tid < 64) {
        int bv = (tid < SCAN_NB)
            ? __hip_atomic_load(&bsums[tid], __ATOMIC_RELAXED, __HIP_MEMORY_SCOPE_AGENT) : 0;
        int s = bv;
#pragma unroll
        for (int off = 1; off < 64; off <<= 1) {
            int u = __shfl_up(s, off, 64);
            if (tid >= off) s += u;
        }
        sh_pref[tid] = s - bv;  // exclusive
    }
    __syncthreads();
    int boff = sh_pref[blockIdx.x];
    if (base == 0) rowp[0] = 0;
    if (base + 0 < NN) rowp[base + 1] = v.x + add + boff;
    if (base + 1 < NN) rowp[base + 2] = v.y + add + boff;
    if (base + 2 < NN) rowp[base + 3] = v.z + add + boff;
    if (base + 3 < NN) rowp[base + 4] = v.w + add + boff;
}

// ---------------- MFMA GEMM body + alpha epilogue ----------------
template<int MOUT, int H>
__device__ __forceinline__ void gemm_body(int bid, const __half* __restrict__ X,
                                          const __half* __restrict__ WT,
                                          const float* __restrict__ aS,
                                          const float* __restrict__ aD,
                                          __half* __restrict__ Ho,
                                          float* __restrict__ osrc,
                                          float* __restrict__ odst,
                                          __half* wlds) {
    constexpr int NT = (MOUT + 15) / 16;
    constexpr int NR = NT * 16;
    const int tid = threadIdx.x;
    for (int i = tid * 8; i < MOUT * 128; i += 2048) {
        half8 v = *(const half8*)&WT[i];
        *(half8*)&wlds[(i >> 7) * 136 + (i & 127)] = v;
    }
    if (NR > MOUT) {
        for (int i = tid * 8; i < (NR - MOUT) * 128; i += 2048) {
            half8 z = {};
            *(half8*)&wlds[(MOUT + (i >> 7)) * 136 + (i & 127)] = z;
        }
    }
    __syncthreads();

    const int lane = tid & 63;
    const int wid = tid >> 6;
    const int r0 = bid * 64 + wid * 16;
    const int arow = r0 + (lane & 15);
    const int lrow = (arow < NN) ? arow : (NN - 1);
    const int koff = (lane >> 4) * 8;
    const size_t xbase = (size_t)lrow * 128 + koff;
    half8 a0 = *(const half8*)&X[xbase];
    half8 a1 = *(const half8*)&X[xbase + 32];
    half8 a2 = *(const half8*)&X[xbase + 64];
    half8 a3 = *(const half8*)&X[xbase + 96];

    floatx4 acc[NT];
#pragma unroll
    for (int t = 0; t < NT; ++t) acc[t] = (floatx4){0.f, 0.f, 0.f, 0.f};

#pragma unroll
    for (int t = 0; t < NT; ++t) {
        const __half* wp = &wlds[(t * 16 + (lane & 15)) * 136 + koff];
        half8 b0 = *(const half8*)&wp[0];
        half8 b1 = *(const half8*)&wp[32];
        half8 b2 = *(const half8*)&wp[64];
        half8 b3 = *(const half8*)&wp[96];
        acc[t] = __builtin_amdgcn_mfma_f32_16x16x32_f16(a0, b0, acc[t], 0, 0, 0);
        acc[t] = __builtin_amdgcn_mfma_f32_16x16x32_f16(a1, b1, acc[t], 0, 0, 0);
        acc[t] = __builtin_amdgcn_mfma_f32_16x16x32_f16(a2, b2, acc[t], 0, 0, 0);
        acc[t] = __builtin_amdgcn_mfma_f32_16x16x32_f16(a3, b3, acc[t], 0, 0, 0);
    }

    const int cc = lane & 15;
    const int rbase = r0 + (lane >> 4) * 4;
    float ps[H][4], pd[H][4];
#pragma unroll
    for (int h = 0; h < H; ++h)
#pragma unroll
        for (int r = 0; r < 4; ++r) { ps[h][r] = 0.f; pd[h][r] = 0.f; }

#pragma unroll
    for (int t = 0; t < NT; ++t) {
        const int col = t * 16 + cc;
        const bool cv = (col < MOUT);
        const float as_ = cv ? aS[col] : 0.f;
        const float ad_ = cv ? aD[col] : 0.f;
        const int h = (H == 2) ? (t >> 2) : 0;
#pragma unroll
        for (int r = 0; r < 4; ++r) {
            ps[h][r] = fmaf(acc[t][r], as_, ps[h][r]);
            pd[h][r] = fmaf(acc[t][r], ad_, pd[h][r]);
        }
    }

    if constexpr (MOUT == 128) {
        __syncthreads();
        const int rowbase = wid * 16;
#pragma unroll
        for (int t = 0; t < NT; ++t)
#pragma unroll
            for (int r = 0; r < 4; ++r)
                wlds[(rowbase + (lane >> 4) * 4 + r) * 136 + t * 16 + cc] =
                    __float2half(acc[t][r]);
        __syncthreads();
#pragma unroll
        for (int p2 = 0; p2 < 4; ++p2) {
            int f = (p2 * 64 + lane) * 8;
            int row = f >> 7, col = f & 127;
            h2x4 v = *(h2x4*)&wlds[(rowbase + row) * 136 + col];
            int grow = r0 + row;
            if (grow < NN) *(h2x4*)&Ho[(size_t)grow * 128 + col] = v;
        }
    } else {
#pragma unroll
        for (int t = 0; t < NT; ++t) {
            const int col = t * 16 + cc;
            const bool cv = (col < MOUT);
#pragma unroll
            for (int r = 0; r < 4; ++r) {
                const int m = rbase + r;
                if (cv && m < NN) Ho[(size_t)m * MOUT + col] = __float2half(acc[t][r]);
            }
        }
    }

#pragma unroll
    for (int off = 1; off <= 8; off <<= 1) {
#pragma unroll
        for (int h = 0; h < H; ++h)
#pragma unroll
            for (int r = 0; r < 4; ++r) {
                ps[h][r] += __shfl_xor(ps[h][r], off, 64);
                pd[h][r] += __shfl_xor(pd[h][r], off, 64);
            }
    }
    if (cc == 0) {
#pragma unroll
        for (int r = 0; r < 4; ++r) {
            const int m = rbase + r;
            if (m < NN) {
#pragma unroll
                for (int h = 0; h < H; ++h) {
                    osrc[m * H + h] = ps[h][r];
                    odst[m * H + h] = pd[h][r];
                }
            }
        }
    }
}

__global__ __launch_bounds__(256) void gemm16_k128(const __half* __restrict__ X,
                                                   const __half* __restrict__ WT,
                                                   const float* __restrict__ aS,
                                                   const float* __restrict__ aD,
                                                   __half* __restrict__ Ho,
                                                   float* __restrict__ osrc,
                                                   float* __restrict__ odst) {
    __shared__ __half wlds[128 * 136];
    gemm_body<128, 2>(blockIdx.x, X, WT, aS, aD, Ho, osrc, odst, wlds);
}

__global__ __launch_bounds__(256) void gemm16_k40(const __half* __restrict__ X,
                                                  const __half* __restrict__ WT,
                                                  const float* __restrict__ aS,
                                                  const float* __restrict__ aD,
                                                  __half* __restrict__ Ho,
                                                  float* __restrict__ osrc,
                                                  float* __restrict__ odst) {
    __shared__ __half wlds[48 * 136];
    gemm_body<40, 1>(blockIdx.x, X, WT, aS, aD, Ho, osrc, odst, wlds);
}

__global__ __launch_bounds__(256) void gemm1_scat(const __half* __restrict__ X,
                                                  const __half* __restrict__ WT,
                                                  const float* __restrict__ aS,
                                                  const float* __restrict__ aD,
                                                  __half* __restrict__ Ho,
                                                  float* __restrict__ osrc,
                                                  float* __restrict__ odst,
                                                  const int* __restrict__ ei,
                                                  const int* __restrict__ rowp,
                                                  const int* __restrict__ rank,
                                                  int* __restrict__ csr_src) {
    __shared__ __half wlds[128 * 136];
    if (blockIdx.x < GEMM_BLKS) {
        gemm_body<128, 2>(blockIdx.x, X, WT, aS, aD, Ho, osrc, odst, wlds);
        return;
    }
    int e = (blockIdx.x - GEMM_BLKS) * 256 + threadIdx.x;
    if (e >= E2) return;
    int s, d; edge_sd(ei, e, s, d);
    csr_src[rowp[d] + rank[e]] = s;
}

// ---------------- fused softmax + aggregation (fp16 gather), no max pass ----------------
__global__ __launch_bounds__(256) void agg_h2(const int* __restrict__ rowp,
                                              const int* __restrict__ csr_src,
                                              const __half* __restrict__ Hf,
                                              const float* __restrict__ osrc,
                                              const float* __restrict__ odst,
                                              const float* __restrict__ bias,
                                              __half* __restrict__ outp) {
    int n = blockIdx.x * 4 + (threadIdx.x >> 6);
    if (n >= NN) return;
    int lane = threadIdx.x & 63;
    int i0 = rowp[n], i1 = rowp[n + 1];
    int c = lane & 15;
    int slot = lane >> 4;
    int c8 = c * 8;
    int h2 = c >> 3;
    float adh = odst[n * 2 + h2];
    bool pl = ((c & 7) == 0);

    float4 lo0{0.f,0.f,0.f,0.f}, hi0{0.f,0.f,0.f,0.f};
    float4 lo1{0.f,0.f,0.f,0.f}, hi1{0.f,0.f,0.f,0.f};
    float psum = 0.f;

    int idx = i0 + slot;
    for (; idx + 12 < i1; idx += 16) {
        int s0 = csr_src[idx];
        int s1 = csr_src[idx + 4];
        int s2 = csr_src[idx + 8];
        int s3 = csr_src[idx + 12];
        float e0 = osrc[s0 * 2 + h2] + adh;
        float e1 = osrc[s1 * 2 + h2] + adh;
        float e2 = osrc[s2 * 2 + h2] + adh;
        float e3 = osrc[s3 * 2 + h2] + adh;
        e0 = (e0 >= 0.f) ? e0 : 0.2f * e0;
        e1 = (e1 >= 0.f) ? e1 : 0.2f * e1;
        e2 = (e2 >= 0.f) ? e2 : 0.2f * e2;
        e3 = (e3 >= 0.f) ? e3 : 0.2f * e3;
        float p0 = __expf(e0), p1 = __expf(e1), p2 = __expf(e2), p3 = __expf(e3);
        h2x4 hv0 = *(const h2x4*)&Hf[(size_t)s0 * 128 + c8];
        h2x4 hv1 = *(const h2x4*)&Hf[(size_t)s1 * 128 + c8];
        h2x4 hv2 = *(const h2x4*)&Hf[(size_t)s2 * 128 + c8];
        h2x4 hv3 = *(const h2x4*)&Hf[(size_t)s3 * 128 + c8];
        if (pl) psum += (p0 + p1) + (p2 + p3);
        float2 f;
        f = __half22float2(hv0.a); lo0.x = fmaf(f.x, p0, lo0.x); lo0.y = fmaf(f.y, p0, lo0.y);
        f = __half22float2(hv0.b); lo0.z = fmaf(f.x, p0, lo0.z); lo0.w = fmaf(f.y, p0, lo0.w);
        f = __half22float2(hv0.c); hi0.x = fmaf(f.x, p0, hi0.x); hi0.y = fmaf(f.y, p0, hi0.y);
        f = __half22float2(hv0.d); hi0.z = fmaf(f.x, p0, hi0.z); hi0.w = fmaf(f.y, p0, hi0.w);
        f = __half22float2(hv1.a); lo0.x = fmaf(f.x, p1, lo0.x); lo0.y = fmaf(f.y, p1, lo0.y);
        f = __half22float2(hv1.b); lo0.z = fmaf(f.x, p1, lo0.z); lo0.w = fmaf(f.y, p1, lo0.w);
        f = __half22float2(hv1.c); hi0.x = fmaf(f.x, p1, hi0.x); hi0.y = fmaf(f.y, p1, hi0.y);
        f = __half22float2(hv1.d); hi0.z = fmaf(f.x, p1, hi0.z); hi0.w = fmaf(f.y, p1, hi0.w);
        f = __half22float2(hv2.a); lo1.x = fmaf(f.x, p2, lo1.x); lo1.y = fmaf(f.y, p2, lo1.y);
        f = __half22float2(hv2.b); lo1.z = fmaf(f.x, p2, lo1.z); lo1.w = fmaf(f.y, p2, lo1.w);
        f = __half22float2(hv2.c); hi1.x = fmaf(f.x, p2, hi1.x); hi1.y = fmaf(f.y, p2, hi1.y);
        f = __half22float2(hv2.d); hi1.z = fmaf(f.x, p2, hi1.z); hi1.w = fmaf(f.y, p2, hi1.w);
        f = __half22float2(hv3.a); lo1.x = fmaf(f.x, p3, lo1.x); lo1.y = fmaf(f.y, p3, lo1.y);
        f = __half22float2(hv3.b); lo1.z = fmaf(f.x, p3, lo1.z); lo1.w = fmaf(f.y, p3, lo1.w);
        f = __half22float2(hv3.c); hi1.x = fmaf(f.x, p3, hi1.x); hi1.y = fmaf(f.y, p3, hi1.y);
        f = __half22float2(hv3.d); hi1.z = fmaf(f.x, p3, hi1.z); hi1.w = fmaf(f.y, p3, hi1.w);
    }
    // tail: <=3 edges per slot, fully predicated & independent (12 loads in flight)
    {
        int id1 = idx + 4, id2 = idx + 8;
        bool v0 = idx < i1, v1 = id1 < i1, v2 = id2 < i1;
        int lim = i1 - 1;
        int s0 = csr_src[min(idx, lim)];
        int s1 = csr_src[min(id1, lim)];
        int s2 = csr_src[min(id2, lim)];
        float e0 = osrc[s0 * 2 + h2] + adh;
        float e1 = osrc[s1 * 2 + h2] + adh;
        float e2 = osrc[s2 * 2 + h2] + adh;
        e0 = (e0 >= 0.f) ? e0 : 0.2f * e0;
        e1 = (e1 >= 0.f) ? e1 : 0.2f * e1;
        e2 = (e2 >= 0.f) ? e2 : 0.2f * e2;
        float p0 = v0 ? __expf(e0) : 0.f;
        float p1 = v1 ? __expf(e1) : 0.f;
        float p2 = v2 ? __expf(e2) : 0.f;
        h2x4 hv0 = *(const h2x4*)&Hf[(size_t)s0 * 128 + c8];
        h2x4 hv1 = *(const h2x4*)&Hf[(size_t)s1 * 128 + c8];
        h2x4 hv2 = *(const h2x4*)&Hf[(size_t)s2 * 128 + c8];
        if (pl) psum += (p0 + p1) + p2;
        float2 f;
        f = __half22float2(hv0.a); lo0.x = fmaf(f.x, p0, lo0.x); lo0.y = fmaf(f.y, p0, lo0.y);
        f = __half22float2(hv0.b); lo0.z = fmaf(f.x, p0, lo0.z); lo0.w = fmaf(f.y, p0, lo0.w);
        f = __half22float2(hv0.c); hi0.x = fmaf(f.x, p0, hi0.x); hi0.y = fmaf(f.y, p0, hi0.y);
        f = __half22float2(hv0.d); hi0.z = fmaf(f.x, p0, hi0.z); hi0.w = fmaf(f.y, p0, hi0.w);
        f = __half22float2(hv1.a); lo0.x = fmaf(f.x, p1, lo0.x); lo0.y = fmaf(f.y, p1, lo0.y);
        f = __half22float2(hv1.b); lo0.z = fmaf(f.x, p1, lo0.z); lo0.w = fmaf(f.y, p1, lo0.w);
        f = __half22float2(hv1.c); hi0.x = fmaf(f.x, p1, hi0.x); hi0.y = fmaf(f.y, p1, hi0.y);
        f = __half22float2(hv1.d); hi0.z = fmaf(f.x, p1, hi0.z); hi0.w = fmaf(f.y, p1, hi0.w);
        f = __half22float2(hv2.a); lo1.x = fmaf(f.x, p2, lo1.x); lo1.y = fmaf(f.y, p2, lo1.y);
        f = __half22float2(hv2.b); lo1.z = fmaf(f.x, p2, lo1.z); lo1.w = fmaf(f.y, p2, lo1.w);
        f = __half22float2(hv2.c); hi1.x = fmaf(f.x, p2, hi1.x); hi1.y = fmaf(f.y, p2, hi1.y);
        f = __half22float2(hv2.d); hi1.z = fmaf(f.x, p2, hi1.z); hi1.w = fmaf(f.y, p2, hi1.w);
    }
    float4 lo{lo0.x + lo1.x, lo0.y + lo1.y, lo0.z + lo1.z, lo0.w + lo1.w};
    float4 hi{hi0.x + hi1.x, hi0.y + hi1.y, hi0.z + hi1.z, hi0.w + hi1.w};
#pragma unroll
    for (int off = 16; off <= 32; off <<= 1) {
        lo.x += __shfl_xor(lo.x, off, 64); lo.y += __shfl_xor(lo.y, off, 64);
        lo.z += __shfl_xor(lo.z, off, 64); lo.w += __shfl_xor(lo.w, off, 64);
        hi.x += __shfl_xor(hi.x, off, 64); hi.y += __shfl_xor(hi.y, off, 64);
        hi.z += __shfl_xor(hi.z, off, 64); hi.w += __shfl_xor(hi.w, off, 64);
        psum += __shfl_xor(psum, off, 64);
    }
    float sh = __shfl(psum, h2 * 8, 64);
    float inv = 1.f / (sh + 1e-16f);
    if (lane < 16) {
        float4 bl = *(const float4*)&bias[c8];
        float4 bh = *(const float4*)&bias[c8 + 4];
        float o0 = fmaf(lo.x, inv, bl.x), o1 = fmaf(lo.y, inv, bl.y);
        float o2 = fmaf(lo.z, inv, bl.z), o3 = fmaf(lo.w, inv, bl.w);
        float o4 = fmaf(hi.x, inv, bh.x), o5 = fmaf(hi.y, inv, bh.y);
        float o6 = fmaf(hi.z, inv, bh.z), o7 = fmaf(hi.w, inv, bh.w);
        o0 = (o0 > 0.f) ? o0 : (__expf(o0) - 1.f);
        o1 = (o1 > 0.f) ? o1 : (__expf(o1) - 1.f);
        o2 = (o2 > 0.f) ? o2 : (__expf(o2) - 1.f);
        o3 = (o3 > 0.f) ? o3 : (__expf(o3) - 1.f);
        o4 = (o4 > 0.f) ? o4 : (__expf(o4) - 1.f);
        o5 = (o5 > 0.f) ? o5 : (__expf(o5) - 1.f);
        o6 = (o6 > 0.f) ? o6 : (__expf(o6) - 1.f);
        o7 = (o7 > 0.f) ? o7 : (__expf(o7) - 1.f);
        h2x4 st;
        st.a = __floats2half2_rn(o0, o1);
        st.b = __floats2half2_rn(o2, o3);
        st.c = __floats2half2_rn(o4, o5);
        st.d = __floats2half2_rn(o6, o7);
        *(h2x4*)&outp[(size_t)n * 128 + c8] = st;
    }
}

__global__ __launch_bounds__(256) void agg_h1(const int* __restrict__ rowp,
                                              const int* __restrict__ csr_src,
                                              const __half* __restrict__ Hf,
                                              const float* __restrict__ osrc,
                                              const float* __restrict__ odst,
                                              const float* __restrict__ bias,
                                              float* __restrict__ outp) {
    int n = blockIdx.x * 4 + (threadIdx.x >> 6);
    if (n >= NN) return;
    int lane = threadIdx.x & 63;
    int i0 = rowp[n], i1 = rowp[n + 1];
    float ad = odst[n];
    int c = lane & 15;
    int slot = lane >> 4;
    bool cl = (c < 10);
    bool pl = (c == 0);
    float4 acc0{0.f,0.f,0.f,0.f}, acc1{0.f,0.f,0.f,0.f};
    float psum = 0.f;

    int idx = i0 + slot;
    for (; idx + 12 < i1; idx += 16) {
        int s0 = csr_src[idx];
        int s1 = csr_src[idx + 4];
        int s2 = csr_src[idx + 8];
        int s3 = csr_src[idx + 12];
        float e0 = osrc[s0] + ad, e1 = osrc[s1] + ad;
        float e2 = osrc[s2] + ad, e3 = osrc[s3] + ad;
        e0 = (e0 >= 0.f) ? e0 : 0.2f * e0;
        e1 = (e1 >= 0.f) ? e1 : 0.2f * e1;
        e2 = (e2 >= 0.f) ? e2 : 0.2f * e2;
        e3 = (e3 >= 0.f) ? e3 : 0.2f * e3;
        float p0 = __expf(e0), p1 = __expf(e1), p2 = __expf(e2), p3 = __expf(e3);
        if (pl) psum += (p0 + p1) + (p2 + p3);
        if (cl) {
            h2x2 hv0 = *(const h2x2*)&Hf[(size_t)s0 * 40 + c * 4];
            h2x2 hv1 = *(const h2x2*)&Hf[(size_t)s1 * 40 + c * 4];
            h2x2 hv2 = *(const h2x2*)&Hf[(size_t)s2 * 40 + c * 4];
            h2x2 hv3 = *(const h2x2*)&Hf[(size_t)s3 * 40 + c * 4];
            float2 f;
            f = __half22float2(hv0.a); acc0.x = fmaf(f.x, p0, acc0.x); acc0.y = fmaf(f.y, p0, acc0.y);
            f = __half22float2(hv0.b); acc0.z = fmaf(f.x, p0, acc0.z); acc0.w = fmaf(f.y, p0, acc0.w);
            f = __half22float2(hv1.a); acc1.x = fmaf(f.x, p1, acc1.x); acc1.y = fmaf(f.y, p1, acc1.y);
            f = __half22float2(hv1.b); acc1.z = fmaf(f.x, p1, acc1.z); acc1.w = fmaf(f.y, p1, acc1.w);
            f = __half22float2(hv2.a); acc0.x = fmaf(f.x, p2, acc0.x); acc0.y = fmaf(f.y, p2, acc0.y);
            f = __half22float2(hv2.b); acc0.z = fmaf(f.x, p2, acc0.z); acc0.w = fmaf(f.y, p2, acc0.w);
            f = __half22float2(hv3.a); acc1.x = fmaf(f.x, p3, acc1.x); acc1.y = fmaf(f.y, p3, acc1.y);
            f = __half22float2(hv3.b); acc1.z = fmaf(f.x, p3, acc1.z); acc1.w = fmaf(f.y, p3, acc1.w);
        }
    }
    // tail: <=3 predicated edges
    {
        int id1 = idx + 4, id2 = idx + 8;
        bool v0 = idx < i1, v1 = id1 < i1, v2 = id2 < i1;
        int lim = i1 - 1;
        int s0 = csr_src[min(idx, lim)];
        int s1 = csr_src[min(id1, lim)];
        int s2 = csr_src[min(id2, lim)];
        float e0 = osrc[s0] + ad, e1 = osrc[s1] + ad, e2 = osrc[s2] + ad;
        e0 = (e0 >= 0.f) ? e0 : 0.2f * e0;
        e1 = (e1 >= 0.f) ? e1 : 0.2f * e1;
        e2 = (e2 >= 0.f) ? e2 : 0.2f * e2;
        float p0 = v0 ? __expf(e0) : 0.f;
        float p1 = v1 ? __expf(e1) : 0.f;
        float p2 = v2 ? __expf(e2) : 0.f;
        if (pl) psum += (p0 + p1) + p2;
        if (cl) {
            h2x2 hv0 = *(const h2x2*)&Hf[(size_t)s0 * 40 + c * 4];
            h2x2 hv1 = *(const h2x2*)&Hf[(size_t)s1 * 40 + c * 4];
            h2x2 hv2 = *(const h2x2*)&Hf[(size_t)s2 * 40 + c * 4];
            float2 f;
            f = __half22float2(hv0.a); acc0.x = fmaf(f.x, p0, acc0.x); acc0.y = fmaf(f.y, p0, acc0.y);
            f = __half22float2(hv0.b); acc0.z = fmaf(f.x, p0, acc0.z); acc0.w = fmaf(f.y, p0, acc0.w);
            f = __half22float2(hv1.a); acc1.x = fmaf(f.x, p1, acc1.x); acc1.y = fmaf(f.y, p1, acc1.y);
            f = __half22float2(hv1.b); acc1.z = fmaf(f.x, p1, acc1.z); acc1.w = fmaf(f.y, p1, acc1.w);
            f = __half22float2(hv2.a); acc0.x = fmaf(f.x, p2, acc0.x); acc0.y = fmaf(f.y, p2, acc0.y);
            f = __half22float2(hv2.b); acc0.z = fmaf(f.x, p2, acc0.z); acc0.w = fmaf(f.y, p2, acc0.w);
        }
    }
    float4 acc{acc0.x + acc1.x, acc0.y + acc1.y, acc0.z + acc1.z, acc0.w + acc1.w};
#pragma unroll
    for (int off = 16; off <= 32; off <<= 1) {
        acc.x += __shfl_xor(acc.x, off, 64);
        acc.y += __shfl_xor(acc.y, off, 64);
        acc.z += __shfl_xor(acc.z, off, 64);
        acc.w += __shfl_xor(acc.w, off, 64);
        psum += __shfl_xor(psum, off, 64);
    }
    float sh = __shfl(psum, 0, 64);
    float inv = 1.f / (sh + 1e-16f);
    if (lane < 10) {
        float4 b = *(const float4*)&bias[lane * 4];
        float4 o;
        o.x = fmaf(acc.x, inv, b.x);
        o.y = fmaf(acc.y, inv, b.y);
        o.z = fmaf(acc.z, inv, b.z);
        o.w = fmaf(acc.w, inv, b.w);
        *(float4*)&outp[(size_t)n * 40 + lane * 4] = o;
    }
}

extern "C" void kernel_launch(void* const* d_in, const int* in_sizes, int n_in,
                              void* d_out, int out_size, void* d_ws, size_t ws_size,
                              hipStream_t stream) {
    const float* x   = (const float*)d_in[0];
    const int*   ei  = (const int*)d_in[1];
    const float* w1  = (const float*)d_in[2];
    const float* as1 = (const float*)d_in[3];
    const float* ad1 = (const float*)d_in[4];
    const float* b1  = (const float*)d_in[5];
    const float* w2  = (const float*)d_in[6];
    const float* as2 = (const float*)d_in[7];
    const float* ad2 = (const float*)d_in[8];
    const float* b2  = (const float*)d_in[9];
    const float* w3  = (const float*)d_in[10];
    const float* as3 = (const float*)d_in[11];
    const float* ad3 = (const float*)d_in[12];
    const float* b3  = (const float*)d_in[13];
    float* out = (float*)d_out;

    char* p = (char*)d_ws;
    __half* x16   = (__half*)p; p += (size_t)NN * 128 * 2;
    __half* h16   = (__half*)p; p += (size_t)NN * 128 * 2;
    __half* f16   = (__half*)p; p += (size_t)NN * 128 * 2;
    __half* wt1   = (__half*)p; p += (size_t)128 * 128 * 2;
    __half* wt2   = (__half*)p; p += (size_t)128 * 128 * 2;
    __half* wt3   = (__half*)p; p += (size_t)64 * 128 * 2;
    float*  osrc  = (float*)p;  p += (size_t)NN * 2 * 4;
    float*  odst  = (float*)p;  p += (size_t)NN * 2 * 4;
    int*    rowp  = (int*)p;    p += (size_t)(NN + 1) * 4;
    int*    deg   = (int*)p;    p += (size_t)NN * 4;   // deg + ctr zeroed together
    int*    ctr   = (int*)p;    p += (size_t)4;
    int*    rank  = (int*)p;    p += (size_t)E2 * 4;
    int*    bsums = (int*)p;    p += (size_t)64 * 4;
    int*    csrsrc= (int*)p;    p += (size_t)E2 * 4;

    const int edgeGrid = cdiv(E2, 256);      // 3321
    const int nodeGrid = cdiv(NN, 4);        // 12500

    hipMemsetAsync(deg, 0, (size_t)(NN + 1) * 4, stream);   // deg + ctr
    prep_rank<<<RANK_BLKS + 1024, 256, 0, stream>>>(ei, deg, rank, x, x16,
                                                    w1, wt1, w2, wt2, w3, wt3);
    scan_all<<<SCAN_NB, 256, 0, stream>>>(deg, rowp, bsums, ctr);

    // ---------- layer 1 (GEMM fused with CSR scatter) ----------
    gemm1_scat<<<GEMM_BLKS + edgeGrid, 256, 0, stream>>>(x16, wt1, as1, ad1, h16,
                                                         osrc, odst, ei, rowp, rank, csrsrc);
    agg_h2<<<nodeGrid, 256, 0, stream>>>(rowp, csrsrc, h16, osrc, odst, b1, f16);

    // ---------- layer 2 ----------
    gemm16_k128<<<GEMM_BLKS, 256, 0, stream>>>(f16, wt2, as2, ad2, h16, osrc, odst);
    agg_h2<<<nodeGrid, 256, 0, stream>>>(rowp, csrsrc, h16, osrc, odst, b2, f16);

    // ---------- layer 3 ----------
    gemm16_k40<<<GEMM_BLKS, 256, 0, stream>>>(f16, wt3, as3, ad3, h16, osrc, odst);
    agg_h1<<<nodeGrid, 256, 0, stream>>>(rowp, csrsrc, h16, osrc, odst, b3, out);
}

// Round 9
// 183.675 us; speedup vs baseline: 1.0892x; 1.0892x over previous
//
#include <hip/hip_runtime.h>
#include <hip/hip_fp16.h>

#define NN 50000
#define NE 800000
#define E2 850000      // NE + NN self-loops
#define SCAN_NB 49     // ceil(NN / 1024)
#define GEMM_BLKS 782  // ceil(NN / 64)
#define P_CH 128       // edge chunks
#define CH 6641        // ceil(E2 / P_CH)
#define HWORDS 12500   // histogram words per half (2 nodes per u32)
#define COLS_BLKS 98   // ceil(25000 / 256)

static inline int cdiv(long long a, int b) { return (int)((a + b - 1) / b); }

using half8  = __attribute__((ext_vector_type(8))) _Float16;
using floatx4 = __attribute__((ext_vector_type(4))) float;

struct __align__(16) h2x4 { __half2 a, b, c, d; };
struct __align__(8)  h2x2 { __half2 a, b; };

__device__ __forceinline__ void edge_sd(const int* __restrict__ ei, int e, int& s, int& d) {
    if (e < NE) { s = ei[e]; d = ei[NE + e]; }
    else { s = e - NE; d = s; }
}

__device__ __forceinline__ half8 cvt_h8(float4 a, float4 b) {
    half8 r;
    r[0] = (_Float16)a.x; r[1] = (_Float16)a.y; r[2] = (_Float16)a.z; r[3] = (_Float16)a.w;
    r[4] = (_Float16)b.x; r[5] = (_Float16)b.y; r[6] = (_Float16)b.z; r[7] = (_Float16)b.w;
    return r;
}

// ---------------- CSR build: LDS histogram, zero global atomics ----------------
// block (c, half): chunk c's edges, nodes [half*25000, half*25000+25000)
__global__ __launch_bounds__(512) void hist_rank(const int* __restrict__ ei,
                                                 unsigned* __restrict__ cnt,
                                                 unsigned short* __restrict__ rank16) {
    __shared__ unsigned hist[HWORDS];
    const int c = blockIdx.x >> 1;
    const int hf = blockIdx.x & 1;
    const int tid = threadIdx.x;
    for (int i = tid; i < HWORDS; i += 512) hist[i] = 0;
    __syncthreads();
    const int e0 = c * CH;
    const int e1 = (e0 + CH < E2) ? e0 + CH : E2;
    const int wlo = hf * HWORDS;
    for (int e = e0 + tid; e < e1; e += 512) {
        int d = (e < NE) ? ei[NE + e] : (e - NE);
        int w = (d >> 1) - wlo;
        if ((unsigned)w < HWORDS) {
            unsigned sh = (d & 1) * 16;
            unsigned old = atomicAdd(&hist[w], 1u << sh);
            rank16[e] = (unsigned short)((old >> sh) & 0xffffu);
        }
    }
    __syncthreads();
    unsigned* dst = &cnt[(size_t)c * 25000 + wlo];
    for (int i = tid; i < HWORDS; i += 512) dst[i] = hist[i];
}

// per-node prefix over chunks (packed u16 pairs) + deg totals; extra blocks: wt cvt + ctr=0
__global__ __launch_bounds__(256) void colscan(const unsigned* __restrict__ cnt,
                                               unsigned* __restrict__ chunkbase,
                                               int* __restrict__ deg,
                                               int* __restrict__ ctr,
                                               const float* __restrict__ w1, __half* __restrict__ wt1,
                                               const float* __restrict__ w2, __half* __restrict__ wt2,
                                               const float* __restrict__ w3, __half* __restrict__ wt3) {
    int b = blockIdx.x;
    if (b < COLS_BLKS) {
        if (b == 0 && threadIdx.x == 0) *ctr = 0;
        int w = b * 256 + threadIdx.x;
        if (w >= 25000) return;
        unsigned run = 0;
#pragma unroll 4
        for (int c = 0; c < P_CH; ++c) {
            unsigned r = cnt[(size_t)c * 25000 + w];
            chunkbase[(size_t)c * 25000 + w] = run;
            run += r;
        }
        deg[2 * w]     = (int)(run & 0xffffu);
        deg[2 * w + 1] = (int)(run >> 16);
        return;
    }
    int tid = (b - COLS_BLKS) * 256 + threadIdx.x;
    int stride = (gridDim.x - COLS_BLKS) * 256;
    for (int i = tid; i < 128 * 128; i += stride)
        wt1[i] = __float2half(w1[(i & 127) * 128 + (i >> 7)]);
    for (int i = tid; i < 128 * 128; i += stride)
        wt2[i] = __float2half(w2[(i & 127) * 128 + (i >> 7)]);
    for (int i = tid; i < 40 * 128; i += stride)
        wt3[i] = __float2half(w3[(i & 127) * 40 + (i >> 7)]);
}

// ---------------- single-kernel two-level scan (49 co-resident blocks + spin) ----------------
__global__ __launch_bounds__(256) void scan_all(const int* __restrict__ deg,
                                                int* __restrict__ rowp,
                                                int* __restrict__ bsums,
                                                int* __restrict__ ctr) {
    __shared__ int wsum[4];
    __shared__ int sh_pref[64];
    int tid = threadIdx.x;
    int base = blockIdx.x * 1024 + tid * 4;
    int4 v = make_int4(0, 0, 0, 0);
    if (base + 3 < NN) v = *(const int4*)&deg[base];
    else {
        if (base + 0 < NN) v.x = deg[base + 0];
        if (base + 1 < NN) v.y = deg[base + 1];
        if (base + 2 < NN) v.z = deg[base + 2];
    }
    v.y += v.x; v.z += v.y; v.w += v.z;
    int lane = tid & 63;
    int wid = tid >> 6;
    int t = v.w;
#pragma unroll
    for (int off = 1; off < 64; off <<= 1) {
        int u = __shfl_up(t, off, 64);
        if (lane >= off) t += u;
    }
    int excl = t - v.w;
    if (lane == 63) wsum[wid] = t;
    __syncthreads();
    int woff = 0;
    for (int w = 0; w < wid; ++w) woff += wsum[w];
    int add = excl + woff;
    if (tid == 255) {
        bsums[blockIdx.x] = add + v.w;
        __threadfence();
        atomicAdd(ctr, 1);
    }
    if (tid == 0) {
        while (__hip_atomic_load(ctr, __ATOMIC_ACQUIRE, __HIP_MEMORY_SCOPE_AGENT) < SCAN_NB) {
            __builtin_amdgcn_s_sleep(8);
        }
    }
    __syncthreads();
    if (tid < 64) {
        int bv = (tid < SCAN_NB)
            ? __hip_atomic_load(&bsums[tid], __ATOMIC_RELAXED, __HIP_MEMORY_SCOPE_AGENT) : 0;
        int s = bv;
#pragma unroll
        for (int off = 1; off < 64; off <<= 1) {
            int u = __shfl_up(s, off, 64);
            if (tid >= off) s += u;
        }
        sh_pref[tid] = s - bv;  // exclusive
    }
    __syncthreads();
    int boff = sh_pref[blockIdx.x];
    if (base == 0) rowp[0] = 0;
    if (base + 0 < NN) rowp[base + 1] = v.x + add + boff;
    if (base + 1 < NN) rowp[base + 2] = v.y + add + boff;
    if (base + 2 < NN) rowp[base + 3] = v.z + add + boff;
    if (base + 3 < NN) rowp[base + 4] = v.w + add + boff;
}

// ---------------- MFMA GEMM body + alpha epilogue ----------------
template<int MOUT, int H, bool XF32>
__device__ __forceinline__ void gemm_body(int bid, const void* __restrict__ Xv,
                                          const __half* __restrict__ WT,
                                          const float* __restrict__ aS,
                                          const float* __restrict__ aD,
                                          __half* __restrict__ Ho,
                                          float* __restrict__ osrc,
                                          float* __restrict__ odst,
                                          __half* wlds) {
    constexpr int NT = (MOUT + 15) / 16;
    constexpr int NR = NT * 16;
    const int tid = threadIdx.x;
    for (int i = tid * 8; i < MOUT * 128; i += 2048) {
        half8 v = *(const half8*)&WT[i];
        *(half8*)&wlds[(i >> 7) * 136 + (i & 127)] = v;
    }
    if (NR > MOUT) {
        for (int i = tid * 8; i < (NR - MOUT) * 128; i += 2048) {
            half8 z = {};
            *(half8*)&wlds[(MOUT + (i >> 7)) * 136 + (i & 127)] = z;
        }
    }
    __syncthreads();

    const int lane = tid & 63;
    const int wid = tid >> 6;
    const int r0 = bid * 64 + wid * 16;
    const int arow = r0 + (lane & 15);
    const int lrow = (arow < NN) ? arow : (NN - 1);
    const int koff = (lane >> 4) * 8;
    half8 a0, a1, a2, a3;
    if constexpr (XF32) {
        const float* Xf = (const float*)Xv;
        const size_t xb = (size_t)lrow * 128 + koff;
        a0 = cvt_h8(*(const float4*)&Xf[xb +  0], *(const float4*)&Xf[xb +  4]);
        a1 = cvt_h8(*(const float4*)&Xf[xb + 32], *(const float4*)&Xf[xb + 36]);
        a2 = cvt_h8(*(const float4*)&Xf[xb + 64], *(const float4*)&Xf[xb + 68]);
        a3 = cvt_h8(*(const float4*)&Xf[xb + 96], *(const float4*)&Xf[xb + 100]);
    } else {
        const __half* Xh = (const __half*)Xv;
        const size_t xb = (size_t)lrow * 128 + koff;
        a0 = *(const half8*)&Xh[xb];
        a1 = *(const half8*)&Xh[xb + 32];
        a2 = *(const half8*)&Xh[xb + 64];
        a3 = *(const half8*)&Xh[xb + 96];
    }

    floatx4 acc[NT];
#pragma unroll
    for (int t = 0; t < NT; ++t) acc[t] = (floatx4){0.f, 0.f, 0.f, 0.f};

#pragma unroll
    for (int t = 0; t < NT; ++t) {
        const __half* wp = &wlds[(t * 16 + (lane & 15)) * 136 + koff];
        half8 b0 = *(const half8*)&wp[0];
        half8 b1 = *(const half8*)&wp[32];
        half8 b2 = *(const half8*)&wp[64];
        half8 b3 = *(const half8*)&wp[96];
        acc[t] = __builtin_amdgcn_mfma_f32_16x16x32_f16(a0, b0, acc[t], 0, 0, 0);
        acc[t] = __builtin_amdgcn_mfma_f32_16x16x32_f16(a1, b1, acc[t], 0, 0, 0);
        acc[t] = __builtin_amdgcn_mfma_f32_16x16x32_f16(a2, b2, acc[t], 0, 0, 0);
        acc[t] = __builtin_amdgcn_mfma_f32_16x16x32_f16(a3, b3, acc[t], 0, 0, 0);
    }

    const int cc = lane & 15;
    const int rbase = r0 + (lane >> 4) * 4;
    float ps[H][4], pd[H][4];
#pragma unroll
    for (int h = 0; h < H; ++h)
#pragma unroll
        for (int r = 0; r < 4; ++r) { ps[h][r] = 0.f; pd[h][r] = 0.f; }

#pragma unroll
    for (int t = 0; t < NT; ++t) {
        const int col = t * 16 + cc;
        const bool cv = (col < MOUT);
        const float as_ = cv ? aS[col] : 0.f;
        const float ad_ = cv ? aD[col] : 0.f;
        const int h = (H == 2) ? (t >> 2) : 0;
#pragma unroll
        for (int r = 0; r < 4; ++r) {
            ps[h][r] = fmaf(acc[t][r], as_, ps[h][r]);
            pd[h][r] = fmaf(acc[t][r], ad_, pd[h][r]);
        }
    }

    if constexpr (MOUT == 128) {
        __syncthreads();
        const int rowbase = wid * 16;
#pragma unroll
        for (int t = 0; t < NT; ++t)
#pragma unroll
            for (int r = 0; r < 4; ++r)
                wlds[(rowbase + (lane >> 4) * 4 + r) * 136 + t * 16 + cc] =
                    __float2half(acc[t][r]);
        __syncthreads();
#pragma unroll
        for (int p2 = 0; p2 < 4; ++p2) {
            int f = (p2 * 64 + lane) * 8;
            int row = f >> 7, col = f & 127;
            h2x4 v = *(h2x4*)&wlds[(rowbase + row) * 136 + col];
            int grow = r0 + row;
            if (grow < NN) *(h2x4*)&Ho[(size_t)grow * 128 + col] = v;
        }
    } else {
#pragma unroll
        for (int t = 0; t < NT; ++t) {
            const int col = t * 16 + cc;
            const bool cv = (col < MOUT);
#pragma unroll
            for (int r = 0; r < 4; ++r) {
                const int m = rbase + r;
                if (cv && m < NN) Ho[(size_t)m * MOUT + col] = __float2half(acc[t][r]);
            }
        }
    }

#pragma unroll
    for (int off = 1; off <= 8; off <<= 1) {
#pragma unroll
        for (int h = 0; h < H; ++h)
#pragma unroll
            for (int r = 0; r < 4; ++r) {
                ps[h][r] += __shfl_xor(ps[h][r], off, 64);
                pd[h][r] += __shfl_xor(pd[h][r], off, 64);
            }
    }
    if (cc == 0) {
#pragma unroll
        for (int r = 0; r < 4; ++r) {
            const int m = rbase + r;
            if (m < NN) {
#pragma unroll
                for (int h = 0; h < H; ++h) {
                    osrc[m * H + h] = ps[h][r];
                    odst[m * H + h] = pd[h][r];
                }
            }
        }
    }
}

__global__ __launch_bounds__(256) void gemm16_k128(const __half* __restrict__ X,
                                                   const __half* __restrict__ WT,
                                                   const float* __restrict__ aS,
                                                   const float* __restrict__ aD,
                                                   __half* __restrict__ Ho,
                                                   float* __restrict__ osrc,
                                                   float* __restrict__ odst) {
    __shared__ __half wlds[128 * 136];
    gemm_body<128, 2, false>(blockIdx.x, X, WT, aS, aD, Ho, osrc, odst, wlds);
}

__global__ __launch_bounds__(256) void gemm16_k40(const __half* __restrict__ X,
                                                  const __half* __restrict__ WT,
                                                  const float* __restrict__ aS,
                                                  const float* __restrict__ aD,
                                                  __half* __restrict__ Ho,
                                                  float* __restrict__ osrc,
                                                  float* __restrict__ odst) {
    __shared__ __half wlds[48 * 136];
    gemm_body<40, 1, false>(blockIdx.x, X, WT, aS, aD, Ho, osrc, odst, wlds);
}

// layer-1 GEMM (fp32 X direct) fused with the atomic-free CSR scatter
__global__ __launch_bounds__(256) void gemm1_scat(const float* __restrict__ X,
                                                  const __half* __restrict__ WT,
                                                  const float* __restrict__ aS,
                                                  const float* __restrict__ aD,
                                                  __half* __restrict__ Ho,
                                                  float* __restrict__ osrc,
                                                  float* __restrict__ odst,
                                                  const int* __restrict__ ei,
                                                  const int* __restrict__ rowp,
                                                  const unsigned short* __restrict__ rank16,
                                                  const unsigned* __restrict__ chunkbase,
                                                  int* __restrict__ csr_src) {
    __shared__ __half wlds[128 * 136];
    if (blockIdx.x < GEMM_BLKS) {
        gemm_body<128, 2, true>(blockIdx.x, X, WT, aS, aD, Ho, osrc, odst, wlds);
        return;
    }
    int e = (blockIdx.x - GEMM_BLKS) * 256 + threadIdx.x;
    if (e >= E2) return;
    int c = e / CH;
    int s, d; edge_sd(ei, e, s, d);
    unsigned cb = chunkbase[(size_t)c * 25000 + (d >> 1)];
    int off = (int)((cb >> ((d & 1) * 16)) & 0xffffu);
    csr_src[rowp[d] + off + (int)rank16[e]] = s;
}

// ---------------- fused softmax + aggregation (fp16 gather), no max pass ----------------
__global__ __launch_bounds__(256) void agg_h2(const int* __restrict__ rowp,
                                              const int* __restrict__ csr_src,
                                              const __half* __restrict__ Hf,
                                              const float* __restrict__ osrc,
                                              const float* __restrict__ odst,
                                              const float* __restrict__ bias,
                                              __half* __restrict__ outp) {
    int n = blockIdx.x * 4 + (threadIdx.x >> 6);
    if (n >= NN) return;
    int lane = threadIdx.x & 63;
    int i0 = rowp[n], i1 = rowp[n + 1];
    int c = lane & 15;
    int slot = lane >> 4;
    int c8 = c * 8;
    int h2 = c >> 3;
    float adh = odst[n * 2 + h2];
    bool pl = ((c & 7) == 0);

    float4 lo0{0.f,0.f,0.f,0.f}, hi0{0.f,0.f,0.f,0.f};
    float4 lo1{0.f,0.f,0.f,0.f}, hi1{0.f,0.f,0.f,0.f};
    float psum = 0.f;

    int idx = i0 + slot;
    for (; idx + 12 < i1; idx += 16) {
        int s0 = csr_src[idx];
        int s1 = csr_src[idx + 4];
        int s2 = csr_src[idx + 8];
        int s3 = csr_src[idx + 12];
        float e0 = osrc[s0 * 2 + h2] + adh;
        float e1 = osrc[s1 * 2 + h2] + adh;
        float e2 = osrc[s2 * 2 + h2] + adh;
        float e3 = osrc[s3 * 2 + h2] + adh;
        e0 = (e0 >= 0.f) ? e0 : 0.2f * e0;
        e1 = (e1 >= 0.f) ? e1 : 0.2f * e1;
        e2 = (e2 >= 0.f) ? e2 : 0.2f * e2;
        e3 = (e3 >= 0.f) ? e3 : 0.2f * e3;
        float p0 = __expf(e0), p1 = __expf(e1), p2 = __expf(e2), p3 = __expf(e3);
        h2x4 hv0 = *(const h2x4*)&Hf[(size_t)s0 * 128 + c8];
        h2x4 hv1 = *(const h2x4*)&Hf[(size_t)s1 * 128 + c8];
        h2x4 hv2 = *(const h2x4*)&Hf[(size_t)s2 * 128 + c8];
        h2x4 hv3 = *(const h2x4*)&Hf[(size_t)s3 * 128 + c8];
        if (pl) psum += (p0 + p1) + (p2 + p3);
        float2 f;
        f = __half22float2(hv0.a); lo0.x = fmaf(f.x, p0, lo0.x); lo0.y = fmaf(f.y, p0, lo0.y);
        f = __half22float2(hv0.b); lo0.z = fmaf(f.x, p0, lo0.z); lo0.w = fmaf(f.y, p0, lo0.w);
        f = __half22float2(hv0.c); hi0.x = fmaf(f.x, p0, hi0.x); hi0.y = fmaf(f.y, p0, hi0.y);
        f = __half22float2(hv0.d); hi0.z = fmaf(f.x, p0, hi0.z); hi0.w = fmaf(f.y, p0, hi0.w);
        f = __half22float2(hv1.a); lo0.x = fmaf(f.x, p1, lo0.x); lo0.y = fmaf(f.y, p1, lo0.y);
        f = __half22float2(hv1.b); lo0.z = fmaf(f.x, p1, lo0.z); lo0.w = fmaf(f.y, p1, lo0.w);
        f = __half22float2(hv1.c); hi0.x = fmaf(f.x, p1, hi0.x); hi0.y = fmaf(f.y, p1, hi0.y);
        f = __half22float2(hv1.d); hi0.z = fmaf(f.x, p1, hi0.z); hi0.w = fmaf(f.y, p1, hi0.w);
        f = __half22float2(hv2.a); lo1.x = fmaf(f.x, p2, lo1.x); lo1.y = fmaf(f.y, p2, lo1.y);
        f = __half22float2(hv2.b); lo1.z = fmaf(f.x, p2, lo1.z); lo1.w = fmaf(f.y, p2, lo1.w);
        f = __half22float2(hv2.c); hi1.x = fmaf(f.x, p2, hi1.x); hi1.y = fmaf(f.y, p2, hi1.y);
        f = __half22float2(hv2.d); hi1.z = fmaf(f.x, p2, hi1.z); hi1.w = fmaf(f.y, p2, hi1.w);
        f = __half22float2(hv3.a); lo1.x = fmaf(f.x, p3, lo1.x); lo1.y = fmaf(f.y, p3, lo1.y);
        f = __half22float2(hv3.b); lo1.z = fmaf(f.x, p3, lo1.z); lo1.w = fmaf(f.y, p3, lo1.w);
        f = __half22float2(hv3.c); hi1.x = fmaf(f.x, p3, hi1.x); hi1.y = fmaf(f.y, p3, hi1.y);
        f = __half22float2(hv3.d); hi1.z = fmaf(f.x, p3, hi1.z); hi1.w = fmaf(f.y, p3, hi1.w);
    }
    // tail: <=3 edges per slot, fully predicated & independent (12 loads in flight)
    {
        int id1 = idx + 4, id2 = idx + 8;
        bool v0 = idx < i1, v1 = id1 < i1, v2 = id2 < i1;
        int lim = i1 - 1;
        int s0 = csr_src[min(idx, lim)];
        int s1 = csr_src[min(id1, lim)];
        int s2 = csr_src[min(id2, lim)];
        float e0 = osrc[s0 * 2 + h2] + adh;
        float e1 = osrc[s1 * 2 + h2] + adh;
        float e2 = osrc[s2 * 2 + h2] + adh;
        e0 = (e0 >= 0.f) ? e0 : 0.2f * e0;
        e1 = (e1 >= 0.f) ? e1 : 0.2f * e1;
        e2 = (e2 >= 0.f) ? e2 : 0.2f * e2;
        float p0 = v0 ? __expf(e0) : 0.f;
        float p1 = v1 ? __expf(e1) : 0.f;
        float p2 = v2 ? __expf(e2) : 0.f;
        h2x4 hv0 = *(const h2x4*)&Hf[(size_t)s0 * 128 + c8];
        h2x4 hv1 = *(const h2x4*)&Hf[(size_t)s1 * 128 + c8];
        h2x4 hv2 = *(const h2x4*)&Hf[(size_t)s2 * 128 + c8];
        if (pl) psum += (p0 + p1) + p2;
        float2 f;
        f = __half22float2(hv0.a); lo0.x = fmaf(f.x, p0, lo0.x); lo0.y = fmaf(f.y, p0, lo0.y);
        f = __half22float2(hv0.b); lo0.z = fmaf(f.x, p0, lo0.z); lo0.w = fmaf(f.y, p0, lo0.w);
        f = __half22float2(hv0.c); hi0.x = fmaf(f.x, p0, hi0.x); hi0.y = fmaf(f.y, p0, hi0.y);
        f = __half22float2(hv0.d); hi0.z = fmaf(f.x, p0, hi0.z); hi0.w = fmaf(f.y, p0, hi0.w);
        f = __half22float2(hv1.a); lo0.x = fmaf(f.x, p1, lo0.x); lo0.y = fmaf(f.y, p1, lo0.y);
        f = __half22float2(hv1.b); lo0.z = fmaf(f.x, p1, lo0.z); lo0.w = fmaf(f.y, p1, lo0.w);
        f = __half22float2(hv1.c); hi0.x = fmaf(f.x, p1, hi0.x); hi0.y = fmaf(f.y, p1, hi0.y);
        f = __half22float2(hv1.d); hi0.z = fmaf(f.x, p1, hi0.z); hi0.w = fmaf(f.y, p1, hi0.w);
        f = __half22float2(hv2.a); lo1.x = fmaf(f.x, p2, lo1.x); lo1.y = fmaf(f.y, p2, lo1.y);
        f = __half22float2(hv2.b); lo1.z = fmaf(f.x, p2, lo1.z); lo1.w = fmaf(f.y, p2, lo1.w);
        f = __half22float2(hv2.c); hi1.x = fmaf(f.x, p2, hi1.x); hi1.y = fmaf(f.y, p2, hi1.y);
        f = __half22float2(hv2.d); hi1.z = fmaf(f.x, p2, hi1.z); hi1.w = fmaf(f.y, p2, hi1.w);
    }
    float4 lo{lo0.x + lo1.x, lo0.y + lo1.y, lo0.z + lo1.z, lo0.w + lo1.w};
    float4 hi{hi0.x + hi1.x, hi0.y + hi1.y, hi0.z + hi1.z, hi0.w + hi1.w};
#pragma unroll
    for (int off = 16; off <= 32; off <<= 1) {
        lo.x += __shfl_xor(lo.x, off, 64); lo.y += __shfl_xor(lo.y, off, 64);
        lo.z += __shfl_xor(lo.z, off, 64); lo.w += __shfl_xor(lo.w, off, 64);
        hi.x += __shfl_xor(hi.x, off, 64); hi.y += __shfl_xor(hi.y, off, 64);
        hi.z += __shfl_xor(hi.z, off, 64); hi.w += __shfl_xor(hi.w, off, 64);
        psum += __shfl_xor(psum, off, 64);
    }
    float sh = __shfl(psum, h2 * 8, 64);
    float inv = 1.f / (sh + 1e-16f);
    if (lane < 16) {
        float4 bl = *(const float4*)&bias[c8];
        float4 bh = *(const float4*)&bias[c8 + 4];
        float o0 = fmaf(lo.x, inv, bl.x), o1 = fmaf(lo.y, inv, bl.y);
        float o2 = fmaf(lo.z, inv, bl.z), o3 = fmaf(lo.w, inv, bl.w);
        float o4 = fmaf(hi.x, inv, bh.x), o5 = fmaf(hi.y, inv, bh.y);
        float o6 = fmaf(hi.z, inv, bh.z), o7 = fmaf(hi.w, inv, bh.w);
        o0 = (o0 > 0.f) ? o0 : (__expf(o0) - 1.f);
        o1 = (o1 > 0.f) ? o1 : (__expf(o1) - 1.f);
        o2 = (o2 > 0.f) ? o2 : (__expf(o2) - 1.f);
        o3 = (o3 > 0.f) ? o3 : (__expf(o3) - 1.f);
        o4 = (o4 > 0.f) ? o4 : (__expf(o4) - 1.f);
        o5 = (o5 > 0.f) ? o5 : (__expf(o5) - 1.f);
        o6 = (o6 > 0.f) ? o6 : (__expf(o6) - 1.f);
        o7 = (o7 > 0.f) ? o7 : (__expf(o7) - 1.f);
        h2x4 st;
        st.a = __floats2half2_rn(o0, o1);
        st.b = __floats2half2_rn(o2, o3);
        st.c = __floats2half2_rn(o4, o5);
        st.d = __floats2half2_rn(o6, o7);
        *(h2x4*)&outp[(size_t)n * 128 + c8] = st;
    }
}

__global__ __launch_bounds__(256) void agg_h1(const int* __restrict__ rowp,
                                              const int* __restrict__ csr_src,
                                              const __half* __restrict__ Hf,
                                              const float* __restrict__ osrc,
                                              const float* __restrict__ odst,
                                              const float* __restrict__ bias,
                                              float* __restrict__ outp) {
    int n = blockIdx.x * 4 + (threadIdx.x >> 6);
    if (n >= NN) return;
    int lane = threadIdx.x & 63;
    int i0 = rowp[n], i1 = rowp[n + 1];
    float ad = odst[n];
    int c = lane & 15;
    int slot = lane >> 4;
    bool cl = (c < 10);
    bool pl = (c == 0);
    float4 acc0{0.f,0.f,0.f,0.f}, acc1{0.f,0.f,0.f,0.f};
    float psum = 0.f;

    int idx = i0 + slot;
    for (; idx + 12 < i1; idx += 16) {
        int s0 = csr_src[idx];
        int s1 = csr_src[idx + 4];
        int s2 = csr_src[idx + 8];
        int s3 = csr_src[idx + 12];
        float e0 = osrc[s0] + ad, e1 = osrc[s1] + ad;
        float e2 = osrc[s2] + ad, e3 = osrc[s3] + ad;
        e0 = (e0 >= 0.f) ? e0 : 0.2f * e0;
        e1 = (e1 >= 0.f) ? e1 : 0.2f * e1;
        e2 = (e2 >= 0.f) ? e2 : 0.2f * e2;
        e3 = (e3 >= 0.f) ? e3 : 0.2f * e3;
        float p0 = __expf(e0), p1 = __expf(e1), p2 = __expf(e2), p3 = __expf(e3);
        if (pl) psum += (p0 + p1) + (p2 + p3);
        if (cl) {
            h2x2 hv0 = *(const h2x2*)&Hf[(size_t)s0 * 40 + c * 4];
            h2x2 hv1 = *(const h2x2*)&Hf[(size_t)s1 * 40 + c * 4];
            h2x2 hv2 = *(const h2x2*)&Hf[(size_t)s2 * 40 + c * 4];
            h2x2 hv3 = *(const h2x2*)&Hf[(size_t)s3 * 40 + c * 4];
            float2 f;
            f = __half22float2(hv0.a); acc0.x = fmaf(f.x, p0, acc0.x); acc0.y = fmaf(f.y, p0, acc0.y);
            f = __half22float2(hv0.b); acc0.z = fmaf(f.x, p0, acc0.z); acc0.w = fmaf(f.y, p0, acc0.w);
            f = __half22float2(hv1.a); acc1.x = fmaf(f.x, p1, acc1.x); acc1.y = fmaf(f.y, p1, acc1.y);
            f = __half22float2(hv1.b); acc1.z = fmaf(f.x, p1, acc1.z); acc1.w = fmaf(f.y, p1, acc1.w);
            f = __half22float2(hv2.a); acc0.x = fmaf(f.x, p2, acc0.x); acc0.y = fmaf(f.y, p2, acc0.y);
            f = __half22float2(hv2.b); acc0.z = fmaf(f.x, p2, acc0.z); acc0.w = fmaf(f.y, p2, acc0.w);
            f = __half22float2(hv3.a); acc1.x = fmaf(f.x, p3, acc1.x); acc1.y = fmaf(f.y, p3, acc1.y);
            f = __half22float2(hv3.b); acc1.z = fmaf(f.x, p3, acc1.z); acc1.w = fmaf(f.y, p3, acc1.w);
        }
    }
    // tail: <=3 predicated edges
    {
        int id1 = idx + 4, id2 = idx + 8;
        bool v0 = idx < i1, v1 = id1 < i1, v2 = id2 < i1;
        int lim = i1 - 1;
        int s0 = csr_src[min(idx, lim)];
        int s1 = csr_src[min(id1, lim)];
        int s2 = csr_src[min(id2, lim)];
        float e0 = osrc[s0] + ad, e1 = osrc[s1] + ad, e2 = osrc[s2] + ad;
        e0 = (e0 >= 0.f) ? e0 : 0.2f * e0;
        e1 = (e1 >= 0.f) ? e1 : 0.2f * e1;
        e2 = (e2 >= 0.f) ? e2 : 0.2f * e2;
        float p0 = v0 ? __expf(e0) : 0.f;
        float p1 = v1 ? __expf(e1) : 0.f;
        float p2 = v2 ? __expf(e2) : 0.f;
        if (pl) psum += (p0 + p1) + p2;
        if (cl) {
            h2x2 hv0 = *(const h2x2*)&Hf[(size_t)s0 * 40 + c * 4];
            h2x2 hv1 = *(const h2x2*)&Hf[(size_t)s1 * 40 + c * 4];
            h2x2 hv2 = *(const h2x2*)&Hf[(size_t)s2 * 40 + c * 4];
            float2 f;
            f = __half22float2(hv0.a); acc0.x = fmaf(f.x, p0, acc0.x); acc0.y = fmaf(f.y, p0, acc0.y);
            f = __half22float2(hv0.b); acc0.z = fmaf(f.x, p0, acc0.z); acc0.w = fmaf(f.y, p0, acc0.w);
            f = __half22float2(hv1.a); acc1.x = fmaf(f.x, p1, acc1.x); acc1.y = fmaf(f.y, p1, acc1.y);
            f = __half22float2(hv1.b); acc1.z = fmaf(f.x, p1, acc1.z); acc1.w = fmaf(f.y, p1, acc1.w);
            f = __half22float2(hv2.a); acc0.x = fmaf(f.x, p2, acc0.x); acc0.y = fmaf(f.y, p2, acc0.y);
            f = __half22float2(hv2.b); acc0.z = fmaf(f.x, p2, acc0.z); acc0.w = fmaf(f.y, p2, acc0.w);
        }
    }
    float4 acc{acc0.x + acc1.x, acc0.y + acc1.y, acc0.z + acc1.z, acc0.w + acc1.w};
#pragma unroll
    for (int off = 16; off <= 32; off <<= 1) {
        acc.x += __shfl_xor(acc.x, off, 64);
        acc.y += __shfl_xor(acc.y, off, 64);
        acc.z += __shfl_xor(acc.z, off, 64);
        acc.w += __shfl_xor(acc.w, off, 64);
        psum += __shfl_xor(psum, off, 64);
    }
    float sh = __shfl(psum, 0, 64);
    float inv = 1.f / (sh + 1e-16f);
    if (lane < 10) {
        float4 b = *(const float4*)&bias[lane * 4];
        float4 o;
        o.x = fmaf(acc.x, inv, b.x);
        o.y = fmaf(acc.y, inv, b.y);
        o.z = fmaf(acc.z, inv, b.z);
        o.w = fmaf(acc.w, inv, b.w);
        *(float4*)&outp[(size_t)n * 40 + lane * 4] = o;
    }
}

extern "C" void kernel_launch(void* const* d_in, const int* in_sizes, int n_in,
                              void* d_out, int out_size, void* d_ws, size_t ws_size,
                              hipStream_t stream) {
    const float* x   = (const float*)d_in[0];
    const int*   ei  = (const int*)d_in[1];
    const float* w1  = (const float*)d_in[2];
    const float* as1 = (const float*)d_in[3];
    const float* ad1 = (const float*)d_in[4];
    const float* b1  = (const float*)d_in[5];
    const float* w2  = (const float*)d_in[6];
    const float* as2 = (const float*)d_in[7];
    const float* ad2 = (const float*)d_in[8];
    const float* b2  = (const float*)d_in[9];
    const float* w3  = (const float*)d_in[10];
    const float* as3 = (const float*)d_in[11];
    const float* ad3 = (const float*)d_in[12];
    const float* b3  = (const float*)d_in[13];
    float* out = (float*)d_out;

    char* p = (char*)d_ws;
    __half*   h16    = (__half*)p;   p += (size_t)NN * 128 * 2;
    __half*   f16    = (__half*)p;   p += (size_t)NN * 128 * 2;
    unsigned* cnt    = (unsigned*)p; p += (size_t)P_CH * 25000 * 4;
    unsigned* cbase  = (unsigned*)p; p += (size_t)P_CH * 25000 * 4;
    __half*   wt1    = (__half*)p;   p += (size_t)128 * 128 * 2;
    __half*   wt2    = (__half*)p;   p += (size_t)128 * 128 * 2;
    __half*   wt3    = (__half*)p;   p += (size_t)64 * 128 * 2;
    float*    osrc   = (float*)p;    p += (size_t)NN * 2 * 4;
    float*    odst   = (float*)p;    p += (size_t)NN * 2 * 4;
    int*      rowp   = (int*)p;      p += (size_t)(NN + 4) * 4;
    int*      deg    = (int*)p;      p += (size_t)NN * 4;
    unsigned short* rank16 = (unsigned short*)p; p += (size_t)E2 * 2;
    int*      bsums  = (int*)p;      p += (size_t)64 * 4;
    int*      ctr    = (int*)p;      p += (size_t)4 * 4;
    int*      csrsrc = (int*)p;      p += (size_t)E2 * 4;

    const int edgeGrid = cdiv(E2, 256);      // 3321
    const int nodeGrid = cdiv(NN, 4);        // 12500

    // ---------- CSR build (LDS histogram, no global atomics) ----------
    hist_rank<<<P_CH * 2, 512, 0, stream>>>(ei, cnt, rank16);
    colscan<<<COLS_BLKS + 64, 256, 0, stream>>>(cnt, cbase, deg, ctr,
                                                w1, wt1, w2, wt2, w3, wt3);
    scan_all<<<SCAN_NB, 256, 0, stream>>>(deg, rowp, bsums, ctr);

    // ---------- layer 1 (fp32-X GEMM fused with CSR scatter) ----------
    gemm1_scat<<<GEMM_BLKS + edgeGrid, 256, 0, stream>>>(x, wt1, as1, ad1, h16,
                                                         osrc, odst, ei, rowp,
                                                         rank16, cbase, csrsrc);
    agg_h2<<<nodeGrid, 256, 0, stream>>>(rowp, csrsrc, h16, osrc, odst, b1, f16);

    // ---------- layer 2 ----------
    gemm16_k128<<<GEMM_BLKS, 256, 0, stream>>>(f16, wt2, as2, ad2, h16, osrc, odst);
    agg_h2<<<nodeGrid, 256, 0, stream>>>(rowp, csrsrc, h16, osrc, odst, b2, f16);

    // ---------- layer 3 ----------
    gemm16_k40<<<GEMM_BLKS, 256, 0, stream>>>(f16, wt3, as3, ad3, h16, osrc, odst);
    agg_h1<<<nodeGrid, 256, 0, stream>>>(rowp, csrsrc, h16, osrc, odst, b3, out);
}